// Round 10
// baseline (109.466 us; speedup 1.0000x reference)
//
#include <hip/hip_runtime.h>
#include <math.h>

// Problem constants (fixed by setup_inputs): B=4, N=8192, P=2048, NSAMPLE=32.
constexpr int Bc  = 4;
constexpr int Nc  = 8192;
constexpr int Pc  = 2048;
constexpr int Sc  = 32;
constexpr int CHc = 34;      // 2 invariance + 4*8 quat channels
constexpr int WSTRIDE = 40;  // ints per query in workspace (32 idx + cnt + pad)
constexpr int NQ  = Bc * Pc; // 8192 queries
// ws layout: [0, NQ*WSTRIDE) ints = idx lists; then 3 SoA float arrays of B*N.
constexpr int SOA_OFF = NQ * WSTRIDE;        // in 4-byte units
constexpr int BN      = Bc * Nc;             // 32768 points total
constexpr int NWIN    = Nc / 512;            // 16 scan windows per batch

// JAX >= 0.4.36 defaults jax_threefry_partitionable=True (validated in R1).
#define THREEFRY_PARTITIONABLE 1

#define FMUL __fmul_rn
#define FADD __fadd_rn
#define FSUB __fsub_rn

__device__ __forceinline__ unsigned tf_rotl(unsigned x, int r) {
  return (x << r) | (x >> (32 - r));
}

// Threefry-2x32, 20 rounds, key = (0, 42)  [jax.random.key(42)]
__device__ __forceinline__ void threefry2x32_k42(unsigned& x0, unsigned& x1) {
  const unsigned ks0 = 0u, ks1 = 42u, ks2 = 0u ^ 42u ^ 0x1BD11BDAu;
  x0 += ks0; x1 += ks1;
#define TF_ROUND(r) { x0 += x1; x1 = tf_rotl(x1, (r)); x1 ^= x0; }
  TF_ROUND(13) TF_ROUND(15) TF_ROUND(26) TF_ROUND(6)
  x0 += ks1; x1 += ks2 + 1u;
  TF_ROUND(17) TF_ROUND(29) TF_ROUND(16) TF_ROUND(24)
  x0 += ks2; x1 += ks0 + 2u;
  TF_ROUND(13) TF_ROUND(15) TF_ROUND(26) TF_ROUND(6)
  x0 += ks0; x1 += ks1 + 3u;
  TF_ROUND(17) TF_ROUND(29) TF_ROUND(16) TF_ROUND(24)
  x0 += ks1; x1 += ks2 + 4u;
  TF_ROUND(13) TF_ROUND(15) TF_ROUND(26) TF_ROUND(6)
  x0 += ks2; x1 += ks0 + 5u;
#undef TF_ROUND
}

// Bit-exact replica of (jax.random.uniform(key(42), (B,1,P,S)) - 0.5) * 2*pi
// at flat counter n. Total count = B*1*P*S = 262144.
__device__ __forceinline__ float jax_rnd_angle(unsigned n) {
#if THREEFRY_PARTITIONABLE
  unsigned x0 = 0u, x1 = n;          // hi32(n)=0, lo32(n)=n
  threefry2x32_k42(x0, x1);
  unsigned bits = x0 ^ x1;
#else
  const unsigned half = (unsigned)(Bc * Pc * Sc) / 2u;  // 131072
  unsigned x0, x1;
  bool second = (n >= half);
  if (second) { x0 = n - half; x1 = n; } else { x0 = n; x1 = n + half; }
  threefry2x32_k42(x0, x1);
  unsigned bits = second ? x1 : x0;
#endif
  float u = __uint_as_float((bits >> 9) | 0x3F800000u) - 1.0f;
  return FMUL(FSUB(u, 0.5f), (float)(2.0 * 3.141592653589793));
}

__device__ __forceinline__ float dot3rn(float ax, float ay, float az,
                                        float bx, float by, float bz) {
  // XLA reduce order over axis of size 3: ((x + y) + z)
  return FADD(FADD(FMUL(ax, bx), FMUL(ay, by)), FMUL(az, bz));
}

// ---------------------------------------------------------------------------
// Kernel 0: AoS -> SoA transpose of xyz into workspace (one-time, 393 KB).
// ---------------------------------------------------------------------------
__global__ __launch_bounds__(256)
void soa_kernel(const float* __restrict__ xyz, float* __restrict__ wsf)
{
  const int i = blockIdx.x * 256 + threadIdx.x;   // point id in [0, B*N)
  if (i < BN) {
    wsf[SOA_OFF + 0 * BN + i] = xyz[i * 3 + 0];
    wsf[SOA_OFF + 1 * BN + i] = xyz[i * 3 + 1];
    wsf[SOA_OFF + 2 * BN + i] = xyz[i * 3 + 2];
  }
}

// ---------------------------------------------------------------------------
// Kernel 1 (R10): COOPERATIVE ball query. One block = 16 queries (4 per
// wave). The block streams 512-point windows into double-buffered LDS once;
// every wave tests each staged point against its 4 centers from registers.
// Cuts per-CU L2 traffic ~16x vs the wave-private scan (R9 probe showed
// ball's cost ~ its L2 traffic, doubled by the post-fill writeback drain).
// d2 arithmetic order identical to before (membership must stay bit-exact).
// Early-exit: per-wave processing skip + block-level LDS done-flags.
// Grid = NQ/16 = 512 blocks = exactly 2 per CU.
// ---------------------------------------------------------------------------
__global__ __launch_bounds__(256)
void ball_kernel(const float* __restrict__ wsf,      // SoA coords in ws
                 const float* __restrict__ new_xyz,  // (B, P, 3)
                 int* __restrict__ ws)
{
  __shared__ float sx[2][512], sy[2][512], sz[2][512];   // 12 KB staging
  __shared__ int   sIdxL[16][Sc];                        // 2 KB result lists
  __shared__ int   sdone[4];

  const int tid  = threadIdx.x;
  const int wave = tid >> 6;
  const int lane = tid & 63;
  const int q0    = blockIdx.x * 16;        // first query of the block
  const int qbase = q0 + wave * 4;          // this wave's 4 queries
  const int b     = q0 >> 11;               // uniform: 16 | 2048

  const float* sxb = wsf + SOA_OFF + 0 * BN + b * Nc;
  const float* syb = wsf + SOA_OFF + 1 * BN + b * Nc;
  const float* szb = wsf + SOA_OFF + 2 * BN + b * Nc;

  // Centers for this wave's 4 queries.
  float cx[4], cy[4], cz[4];
  #pragma unroll
  for (int i = 0; i < 4; ++i) {
    const int p = (qbase + i) & 2047;
    cx[i] = new_xyz[((size_t)b * Pc + p) * 3 + 0];
    cy[i] = new_xyz[((size_t)b * Pc + p) * 3 + 1];
    cz[i] = new_xyz[((size_t)b * Pc + p) * 3 + 2];
  }

  const float R2 = (float)(0.2 * 0.2);
  const unsigned long long below = (1ull << lane) - 1ull;

  // Stage window wnd (512 points) into buffer buf: 256 threads x 2 pts/coord.
  auto stage = [&](int wnd, int buf) {
    const int basep = wnd * 512;
    sx[buf][tid]       = sxb[basep + tid];
    sy[buf][tid]       = syb[basep + tid];
    sz[buf][tid]       = szb[basep + tid];
    sx[buf][tid + 256] = sxb[basep + tid + 256];
    sy[buf][tid + 256] = syb[basep + tid + 256];
    sz[buf][tid + 256] = szb[basep + tid + 256];
  };

  int run4[4] = {0, 0, 0, 0};

  // Process staged window wnd for this wave's 4 queries, in index order.
  auto procwin = [&](int wnd, int buf) {
    #pragma unroll 1
    for (int g = 0; g < 8; ++g) {
      const float px = sx[buf][g * 64 + lane];   // stride-1: 2-way, free
      const float py = sy[buf][g * 64 + lane];
      const float pz = sz[buf][g * 64 + lane];
      #pragma unroll
      for (int i = 0; i < 4; ++i) {
        const float dx = FSUB(cx[i], px);
        const float dy = FSUB(cy[i], py);
        const float dz = FSUB(cz[i], pz);
        const float d2 = FADD(FADD(FMUL(dx, dx), FMUL(dy, dy)), FMUL(dz, dz));
        const bool m = d2 < R2;
        const unsigned long long mask = __ballot(m);
        if (m) {
          const int pos = run4[i] + (int)__popcll(mask & below);
          if (pos < Sc) sIdxL[wave * 4 + i][pos] = wnd * 512 + g * 64 + lane;
        }
        run4[i] += (int)__popcll(mask);   // wave-uniform
      }
    }
  };

  if (tid < 4) sdone[tid] = 0;
  stage(0, 0);
  bool mydone = false;
  int w = 0;
  #pragma unroll 1
  for (;;) {
    __syncthreads();                     // staged w visible; buf[(w+1)&1] free
    if (w >= NWIN) break;
    if ((sdone[0] & sdone[1] & sdone[2] & sdone[3]) != 0) break;
    if (w + 1 < NWIN) stage(w + 1, (w + 1) & 1);
    if (!mydone) {
      procwin(w, w & 1);
      mydone = (run4[0] >= Sc) & (run4[1] >= Sc) &
               (run4[2] >= Sc) & (run4[3] >= Sc);
      if (mydone && lane == 0) sdone[wave] = 1;
    }
    ++w;
  }

  // Flush this wave's 4 queries (same-wave LDS RAW; no barrier needed).
  #pragma unroll
  for (int i = 0; i < 4; ++i) {
    int* wq = ws + (size_t)(qbase + i) * WSTRIDE;
    const int cnt = (run4[i] > Sc) ? Sc : run4[i];
    if (lane < Sc) wq[lane] = sIdxL[wave * 4 + i][lane];  // slots >= cnt are
                                                          // garbage; emit only
                                                          // reads j < cnt
    if (lane == 0) wq[Sc] = cnt;
  }
}

// ---------------------------------------------------------------------------
// Kernel 2: angles, stable sort, invariance + quaternion channels.
// TWO queries per wave (validated R7).
// ---------------------------------------------------------------------------
__global__ __launch_bounds__(256)
void emit_kernel(const float* __restrict__ xyz,      // (B, N, 3)
                 const float* __restrict__ new_xyz,  // (B, P, 3)
                 const int* __restrict__ ws,
                 float* __restrict__ out)            // (B, 34, P, 32)
{
  const int wave = threadIdx.x >> 6;
  const int lane = threadIdx.x & 63;
  const int half = lane >> 5;               // 0 or 1: which query in the wave
  const int hofs = half << 5;               // shuffle-source offset
  const int j    = lane & 31;               // slot within the query
  const int q    = blockIdx.x * 8 + wave * 2 + half;
  const int b    = q >> 11;
  const int p    = q & 2047;

  const float* xb = xyz + (size_t)b * Nc * 3;
  const float cx = new_xyz[((size_t)b * Pc + p) * 3 + 0];
  const float cy = new_xyz[((size_t)b * Pc + p) * 3 + 1];
  const float cz = new_xyz[((size_t)b * Pc + p) * 3 + 2];

  const int* wq = ws + (size_t)q * WSTRIDE;
  const int cnt = wq[Sc];               // clamped to [1, 32] by K1

  const int gi = wq[(j < cnt) ? j : 0];   // pad with 'first'

  const float ptx = xb[gi * 3 + 0];
  const float pty = xb[gi * 3 + 1];
  const float ptz = xb[gi * 3 + 2];
  const float relx = FSUB(ptx, cx);
  const float rely = FSUB(pty, cy);
  const float relz = FSUB(ptz, cz);

  // p1 = normalize(center)  (single normalization; used for vert & sinus & inv)
  const float n1  = __fsqrt_rn(dot3rn(cx, cy, cz, cx, cy, cz));
  const float id1 = FADD(n1, 1e-6f);
  const float p1x = __fdiv_rn(cx, id1);
  const float p1y = __fdiv_rn(cy, id1);
  const float p1z = __fdiv_rn(cz, id1);

  // p2 = normalize(p1) (double normalization inside _project_one)
  const float n2  = __fsqrt_rn(dot3rn(p1x, p1y, p1z, p1x, p1y, p1z));
  const float id2 = FADD(n2, 1e-6f);
  const float p2x = __fdiv_rn(p1x, id2);
  const float p2y = __fdiv_rn(p1y, id2);
  const float p2z = __fdiv_rn(p1z, id2);

  const bool colin = fabsf(p2x) > (float)(1.0 - 0.001);
  const float rxv = colin ? FMUL(-p2y, p2x) : FSUB(1.0f, FMUL(p2x, p2x));
  const float ryv = colin ? FSUB(1.0f, FMUL(p2y, p2y)) : FMUL(-p2x, p2y);
  const float rzv = colin ? FMUL(-p2y, p2z) : FMUL(-p2x, p2z);
  const float nr  = __fsqrt_rn(dot3rn(rxv, ryv, rzv, rxv, ryv, rzv));
  const float idr = FADD(nr, 1e-6f);
  const float refx = __fdiv_rn(rxv, idr);
  const float refy = __fdiv_rn(ryv, idr);
  const float refz = __fdiv_rn(rzv, idr);

  // projs = normalize(rel - (p1.rel)*p1)
  const float sdot = dot3rn(p1x, p1y, p1z, relx, rely, relz);
  const float wx = FSUB(relx, FMUL(sdot, p1x));
  const float wy = FSUB(rely, FMUL(sdot, p1y));
  const float wz = FSUB(relz, FMUL(sdot, p1z));
  const float nw  = __fsqrt_rn(dot3rn(wx, wy, wz, wx, wy, wz));
  const float idw = FADD(nw, 1e-6f);
  const float prx = __fdiv_rn(wx, idw);
  const float pry = __fdiv_rn(wy, idw);
  const float prz = __fdiv_rn(wz, idw);

  const float s2 = dot3rn(prx, pry, prz, prx, pry, prz);

  float angle;
  if (s2 < 1e-12f) {
    const unsigned n = ((unsigned)q << 5) | (unsigned)j;  // flat idx in (B,1,P,S)
    angle = jax_rnd_angle(n);
  } else {
    // cross(ref, projs) . p1  and  ref . projs
    const float ccx = FSUB(FMUL(refy, prz), FMUL(refz, pry));
    const float ccy = FSUB(FMUL(refz, prx), FMUL(refx, prz));
    const float ccz = FSUB(FMUL(refx, pry), FMUL(refy, prx));
    const float sinus   = dot3rn(ccx, ccy, ccz, p1x, p1y, p1z);
    const float cosinus = dot3rn(refx, refy, refz, prx, pry, prz);
    angle = atan2f(sinus, cosinus);
  }

  // ---------------- Stable ascending sort of (angle, j) within each half ---
  const unsigned ab   = __float_as_uint(angle);
  const unsigned skey = (ab & 0x80000000u) ? ~ab : (ab | 0x80000000u);
  unsigned long long key = ((unsigned long long)skey << 32) | (unsigned)j;

  #pragma unroll
  for (int k = 2; k <= 32; k <<= 1) {
    #pragma unroll
    for (int jj = k >> 1; jj > 0; jj >>= 1) {
      const unsigned long long other = __shfl_xor(key, jj);
      const bool up      = ((j & k) == 0);       // use j, not lane (half-local)
      const bool lower   = ((j & jj) == 0);
      const bool takeMin = (lower == up);
      const unsigned long long mn = (key < other) ? key : other;
      const unsigned long long mx = (key < other) ? other : key;
      key = takeMin ? mn : mx;
    }
  }
  const int oj = (int)(key & 31u);   // original slot landing at position j

  // Gather sorted rel via shuffle (source within this half)
  const float sx = __shfl(relx, oj + hofs);
  const float sy = __shfl(rely, oj + hofs);
  const float sz = __shfl(relz, oj + hofs);

  // ---------------- Outputs (2% tolerance: plain f32 math is fine here)
  const float dotr  = sx * sx + sy * sy + sz * sz;
  const float norm2 = sqrtf(dotr + 1e-12f);
  float cosang = (p1x * sx + p1y * sy + p1z * sz) / norm2;
  const float CL = (float)(1.0 - 1e-6);
  cosang = fminf(fmaxf(cosang, -CL), CL);
  const float ainv = acosf(cosang);

  const float dist = sqrtf(dotr);
  const float invd = 1.0f / (dist + 1e-6f);
  const float oxv = sx * invd, oyv = sy * invd, ozv = sz * invd;
  const float theta = (dist / 0.2f) * (float)(3.141592653589793 / 2.0);
  float st, ct;
  sincosf(theta, &st, &ct);
  const float qw = ct, qx = st * oxv, qy = st * oyv, qz = st * ozv;

  const size_t chs   = (size_t)Pc * Sc;
  const size_t baseo = (size_t)b * CHc * chs + (size_t)p * Sc + (size_t)j;

  out[baseo + 0 * chs] = norm2;
  out[baseo + 1 * chs] = ainv;
  // quats: channel = 2 + comp*8 + m ; value at pos s is q_comp[(s+m)%32]
  #pragma unroll
  for (int m = 0; m < 8; ++m) {
    const int src = ((j + m) & 31) + hofs;
    const float vw = __shfl(qw, src);
    const float vx = __shfl(qx, src);
    const float vy = __shfl(qy, src);
    const float vz = __shfl(qz, src);
    out[baseo + (size_t)(2 + 0 * 8 + m) * chs] = vw;
    out[baseo + (size_t)(2 + 1 * 8 + m) * chs] = vx;
    out[baseo + (size_t)(2 + 2 * 8 + m) * chs] = vy;
    out[baseo + (size_t)(2 + 3 * 8 + m) * chs] = vz;
  }
}

extern "C" void kernel_launch(void* const* d_in, const int* in_sizes, int n_in,
                              void* d_out, int out_size, void* d_ws, size_t ws_size,
                              hipStream_t stream) {
  const float* xyz     = (const float*)d_in[0];
  const float* new_xyz = (const float*)d_in[1];
  // d_in[2] (fps_idx) is dead: reference drops the fps column before use.
  float* out = (float*)d_out;
  int*   ws  = (int*)d_ws;      // idx lists (1.31 MB) then SoA coords (393 KB)
  float* wsf = (float*)d_ws;

  hipLaunchKernelGGL(soa_kernel, dim3((BN + 255) / 256), dim3(256), 0, stream,
                     xyz, wsf);

  // ball: 16 queries/block -> 512 blocks (exactly 2 per CU)
  hipLaunchKernelGGL(ball_kernel, dim3(NQ / 16), dim3(256), 0, stream,
                     wsf, new_xyz, ws);

  // emit: 2 queries/wave, 4 waves/block -> 1024 blocks
  hipLaunchKernelGGL(emit_kernel, dim3(NQ / 8), dim3(256), 0, stream,
                     xyz, new_xyz, ws, out);
}

// Round 11
// 84.499 us; speedup vs baseline: 1.2955x; 1.2955x over previous
//
#include <hip/hip_runtime.h>
#include <math.h>

// ============================================================================
// R11: single fused kernel, wave-private throughout (R10 lesson: under the
// post-fill writeback drain, decoupling + occupancy beat traffic tricks).
// One wave owns 2 queries: scan loads each 512-pt window once, tests both
// centers (1.5x traffic cut, window-max of 2 queries); hit indices go to
// 128 B wave-private LDS; the SAME wave then runs the validated half-lane
// emit (R7) with no barrier. No ws, no soa kernel, 1 launch instead of 3.
// ============================================================================

// Problem constants (fixed by setup_inputs): B=4, N=8192, P=2048, NSAMPLE=32.
constexpr int Bc  = 4;
constexpr int Nc  = 8192;
constexpr int Pc  = 2048;
constexpr int Sc  = 32;
constexpr int CHc = 34;      // 2 invariance + 4*8 quat channels
constexpr int NQ  = Bc * Pc; // 8192 queries

// JAX >= 0.4.36 defaults jax_threefry_partitionable=True (validated in R1).
#define THREEFRY_PARTITIONABLE 1

#define FMUL __fmul_rn
#define FADD __fadd_rn
#define FSUB __fsub_rn

__device__ __forceinline__ unsigned tf_rotl(unsigned x, int r) {
  return (x << r) | (x >> (32 - r));
}

// Threefry-2x32, 20 rounds, key = (0, 42)  [jax.random.key(42)]
__device__ __forceinline__ void threefry2x32_k42(unsigned& x0, unsigned& x1) {
  const unsigned ks0 = 0u, ks1 = 42u, ks2 = 0u ^ 42u ^ 0x1BD11BDAu;
  x0 += ks0; x1 += ks1;
#define TF_ROUND(r) { x0 += x1; x1 = tf_rotl(x1, (r)); x1 ^= x0; }
  TF_ROUND(13) TF_ROUND(15) TF_ROUND(26) TF_ROUND(6)
  x0 += ks1; x1 += ks2 + 1u;
  TF_ROUND(17) TF_ROUND(29) TF_ROUND(16) TF_ROUND(24)
  x0 += ks2; x1 += ks0 + 2u;
  TF_ROUND(13) TF_ROUND(15) TF_ROUND(26) TF_ROUND(6)
  x0 += ks0; x1 += ks1 + 3u;
  TF_ROUND(17) TF_ROUND(29) TF_ROUND(16) TF_ROUND(24)
  x0 += ks1; x1 += ks2 + 4u;
  TF_ROUND(13) TF_ROUND(15) TF_ROUND(26) TF_ROUND(6)
  x0 += ks2; x1 += ks0 + 5u;
#undef TF_ROUND
}

// Bit-exact replica of (jax.random.uniform(key(42), (B,1,P,S)) - 0.5) * 2*pi
// at flat counter n. Total count = B*1*P*S = 262144.
__device__ __forceinline__ float jax_rnd_angle(unsigned n) {
#if THREEFRY_PARTITIONABLE
  unsigned x0 = 0u, x1 = n;          // hi32(n)=0, lo32(n)=n
  threefry2x32_k42(x0, x1);
  unsigned bits = x0 ^ x1;
#else
  const unsigned half = (unsigned)(Bc * Pc * Sc) / 2u;  // 131072
  unsigned x0, x1;
  bool second = (n >= half);
  if (second) { x0 = n - half; x1 = n; } else { x0 = n; x1 = n + half; }
  threefry2x32_k42(x0, x1);
  unsigned bits = second ? x1 : x0;
#endif
  float u = __uint_as_float((bits >> 9) | 0x3F800000u) - 1.0f;
  return FMUL(FSUB(u, 0.5f), (float)(2.0 * 3.141592653589793));
}

__device__ __forceinline__ float dot3rn(float ax, float ay, float az,
                                        float bx, float by, float bz) {
  // XLA reduce order over axis of size 3: ((x + y) + z)
  return FADD(FADD(FMUL(ax, bx), FMUL(ay, by)), FMUL(az, bz));
}

// ---------------------------------------------------------------------------
// One wave = 2 queries. Phase 1: double-buffered register-prefetch scan of
// AoS xyz, both centers tested per staged point, ordered first-32 per query
// into wave-private LDS (lgkmcnt only — no global stores in the loop).
// Phase 2 (same wave, no barrier): lanes 0..31 -> query 0, 32..63 -> query 1;
// angles, stable bitonic sort, invariance + quat channels (validated R7).
// ---------------------------------------------------------------------------
__global__ __launch_bounds__(256)
void qgq_fused(const float* __restrict__ xyz,      // (B, N, 3)
               const float* __restrict__ new_xyz,  // (B, P, 3)
               float* __restrict__ out)            // (B, 34, P, 32)
{
  __shared__ int sIdx[4][2 * Sc];           // 256 B per wave, wave-private

  const int wave = threadIdx.x >> 6;
  const int lane = threadIdx.x & 63;
  const int q0   = blockIdx.x * 8 + wave * 2;   // wave's first query
  const int b    = q0 >> 11;                    // uniform per block (8 | 2048)
  const int p0   = q0 & 2047;

  const float* xb = xyz + (size_t)b * Nc * 3;
  const float c0x = new_xyz[((size_t)b * Pc + p0) * 3 + 0];
  const float c0y = new_xyz[((size_t)b * Pc + p0) * 3 + 1];
  const float c0z = new_xyz[((size_t)b * Pc + p0) * 3 + 2];
  const float c1x = new_xyz[((size_t)b * Pc + p0 + 1) * 3 + 0];
  const float c1y = new_xyz[((size_t)b * Pc + p0 + 1) * 3 + 1];
  const float c1z = new_xyz[((size_t)b * Pc + p0 + 1) * 3 + 2];

  int* sw = sIdx[wave];
  const float R2 = (float)(0.2 * 0.2);
  const unsigned long long below = (1ull << lane) - 1ull;

  auto loadw = [&](int basew, float xs[8], float ys[8], float zs[8]) {
    #pragma unroll
    for (int k = 0; k < 8; ++k) {
      const int i = basew + k * 64 + lane;
      xs[k] = xb[i * 3 + 0];
      ys[k] = xb[i * 3 + 1];
      zs[k] = xb[i * 3 + 2];
    }
  };

  int run0 = 0, run1 = 0;
  auto procw = [&](int basew, const float xs[8], const float ys[8],
                   const float zs[8]) {
    #pragma unroll
    for (int k = 0; k < 8; ++k) {
      const int idx = basew + k * 64 + lane;
      {  // query 0 (index order preserved per query)
        const float dx = FSUB(c0x, xs[k]);
        const float dy = FSUB(c0y, ys[k]);
        const float dz = FSUB(c0z, zs[k]);
        const float d2 = FADD(FADD(FMUL(dx, dx), FMUL(dy, dy)), FMUL(dz, dz));
        const bool m = d2 < R2;
        const unsigned long long mask = __ballot(m);
        if (m) {
          const int pos = run0 + (int)__popcll(mask & below);
          if (pos < Sc) sw[pos] = idx;            // LDS, lgkmcnt only
        }
        run0 += (int)__popcll(mask);              // wave-uniform
      }
      {  // query 1
        const float dx = FSUB(c1x, xs[k]);
        const float dy = FSUB(c1y, ys[k]);
        const float dz = FSUB(c1z, zs[k]);
        const float d2 = FADD(FADD(FMUL(dx, dx), FMUL(dy, dy)), FMUL(dz, dz));
        const bool m = d2 < R2;
        const unsigned long long mask = __ballot(m);
        if (m) {
          const int pos = run1 + (int)__popcll(mask & below);
          if (pos < Sc) sw[Sc + pos] = idx;
        }
        run1 += (int)__popcll(mask);
      }
    }
  };

  float ax[8], ay[8], az[8], bx[8], by[8], bz[8];
  loadw(0, ax, ay, az);                 // prefetch window 0
  #pragma unroll 1
  for (int basew = 0; basew < Nc; basew += 1024) {   // 8 double-window steps
    loadw(basew + 512, bx, by, bz);                  // prefetch next (valid)
    procw(basew, ax, ay, az);
    if (run0 >= Sc && run1 >= Sc) break;
    loadw((basew + 1024) & (Nc - 1), ax, ay, az);    // prefetch (wrap-clamped)
    procw(basew + 512, bx, by, bz);
    if (run0 >= Sc && run1 >= Sc) break;
  }

  // -------- Phase 2: same wave, no barrier (same-wave LDS RAW is ordered
  // by the compiler's lgkmcnt). Lanes 0..31 -> q0, 32..63 -> q0+1.
  const int half = lane >> 5;
  const int hofs = half << 5;
  const int j    = lane & 31;
  const int q    = q0 + half;
  const int p    = q & 2047;

  const int c0c = (run0 > Sc) ? Sc : run0;   // >=1: center itself has d2==0
  const int c1c = (run1 > Sc) ? Sc : run1;
  const int cnt = half ? c1c : c0c;
  const float cx = half ? c1x : c0x;
  const float cy = half ? c1y : c0y;
  const float cz = half ? c1z : c0z;

  const int gi = sw[hofs + ((j < cnt) ? j : 0)];   // pad with 'first'

  const float ptx = xb[gi * 3 + 0];
  const float pty = xb[gi * 3 + 1];
  const float ptz = xb[gi * 3 + 2];
  const float relx = FSUB(ptx, cx);
  const float rely = FSUB(pty, cy);
  const float relz = FSUB(ptz, cz);

  // p1 = normalize(center)  (single normalization; used for vert & sinus & inv)
  const float n1  = __fsqrt_rn(dot3rn(cx, cy, cz, cx, cy, cz));
  const float id1 = FADD(n1, 1e-6f);
  const float p1x = __fdiv_rn(cx, id1);
  const float p1y = __fdiv_rn(cy, id1);
  const float p1z = __fdiv_rn(cz, id1);

  // p2 = normalize(p1) (double normalization inside _project_one)
  const float n2  = __fsqrt_rn(dot3rn(p1x, p1y, p1z, p1x, p1y, p1z));
  const float id2 = FADD(n2, 1e-6f);
  const float p2x = __fdiv_rn(p1x, id2);
  const float p2y = __fdiv_rn(p1y, id2);
  const float p2z = __fdiv_rn(p1z, id2);

  const bool colin = fabsf(p2x) > (float)(1.0 - 0.001);
  const float rxv = colin ? FMUL(-p2y, p2x) : FSUB(1.0f, FMUL(p2x, p2x));
  const float ryv = colin ? FSUB(1.0f, FMUL(p2y, p2y)) : FMUL(-p2x, p2y);
  const float rzv = colin ? FMUL(-p2y, p2z) : FMUL(-p2x, p2z);
  const float nr  = __fsqrt_rn(dot3rn(rxv, ryv, rzv, rxv, ryv, rzv));
  const float idr = FADD(nr, 1e-6f);
  const float refx = __fdiv_rn(rxv, idr);
  const float refy = __fdiv_rn(ryv, idr);
  const float refz = __fdiv_rn(rzv, idr);

  // projs = normalize(rel - (p1.rel)*p1)
  const float sdot = dot3rn(p1x, p1y, p1z, relx, rely, relz);
  const float wx = FSUB(relx, FMUL(sdot, p1x));
  const float wy = FSUB(rely, FMUL(sdot, p1y));
  const float wz = FSUB(relz, FMUL(sdot, p1z));
  const float nw  = __fsqrt_rn(dot3rn(wx, wy, wz, wx, wy, wz));
  const float idw = FADD(nw, 1e-6f);
  const float prx = __fdiv_rn(wx, idw);
  const float pry = __fdiv_rn(wy, idw);
  const float prz = __fdiv_rn(wz, idw);

  const float s2 = dot3rn(prx, pry, prz, prx, pry, prz);

  float angle;
  if (s2 < 1e-12f) {
    const unsigned n = ((unsigned)q << 5) | (unsigned)j;  // flat idx (B,1,P,S)
    angle = jax_rnd_angle(n);
  } else {
    // cross(ref, projs) . p1  and  ref . projs
    const float ccx = FSUB(FMUL(refy, prz), FMUL(refz, pry));
    const float ccy = FSUB(FMUL(refz, prx), FMUL(refx, prz));
    const float ccz = FSUB(FMUL(refx, pry), FMUL(refy, prx));
    const float sinus   = dot3rn(ccx, ccy, ccz, p1x, p1y, p1z);
    const float cosinus = dot3rn(refx, refy, refz, prx, pry, prz);
    angle = atan2f(sinus, cosinus);
  }

  // ---------------- Stable ascending sort of (angle, j) within each half ---
  // Key: total-order float bits (matches XLA: -0 < +0, no NaNs here) || j.
  // All xor masks <= 16, so comparisons never cross the 32-lane half.
  const unsigned ab   = __float_as_uint(angle);
  const unsigned skey = (ab & 0x80000000u) ? ~ab : (ab | 0x80000000u);
  unsigned long long key = ((unsigned long long)skey << 32) | (unsigned)j;

  #pragma unroll
  for (int k = 2; k <= 32; k <<= 1) {
    #pragma unroll
    for (int jj = k >> 1; jj > 0; jj >>= 1) {
      const unsigned long long other = __shfl_xor(key, jj);
      const bool up      = ((j & k) == 0);       // j, not lane (half-local)
      const bool lower   = ((j & jj) == 0);
      const bool takeMin = (lower == up);
      const unsigned long long mn = (key < other) ? key : other;
      const unsigned long long mx = (key < other) ? other : key;
      key = takeMin ? mn : mx;
    }
  }
  const int oj = (int)(key & 31u);   // original slot landing at position j

  // Gather sorted rel via shuffle (source within this half)
  const float sx = __shfl(relx, oj + hofs);
  const float sy = __shfl(rely, oj + hofs);
  const float sz = __shfl(relz, oj + hofs);

  // ---------------- Outputs (2% tolerance: plain f32 math is fine here)
  const float dotr  = sx * sx + sy * sy + sz * sz;
  const float norm2 = sqrtf(dotr + 1e-12f);
  float cosang = (p1x * sx + p1y * sy + p1z * sz) / norm2;
  const float CL = (float)(1.0 - 1e-6);
  cosang = fminf(fmaxf(cosang, -CL), CL);
  const float ainv = acosf(cosang);

  const float dist = sqrtf(dotr);
  const float invd = 1.0f / (dist + 1e-6f);
  const float oxv = sx * invd, oyv = sy * invd, ozv = sz * invd;
  const float theta = (dist / 0.2f) * (float)(3.141592653589793 / 2.0);
  float st, ct;
  sincosf(theta, &st, &ct);
  const float qw = ct, qx = st * oxv, qy = st * oyv, qz = st * ozv;

  const size_t chs   = (size_t)Pc * Sc;
  const size_t baseo = (size_t)b * CHc * chs + (size_t)p * Sc + (size_t)j;

  out[baseo + 0 * chs] = norm2;
  out[baseo + 1 * chs] = ainv;
  // quats: channel = 2 + comp*8 + m ; value at pos s is q_comp[(s+m)%32]
  #pragma unroll
  for (int m = 0; m < 8; ++m) {
    const int src = ((j + m) & 31) + hofs;
    const float vw = __shfl(qw, src);
    const float vx = __shfl(qx, src);
    const float vy = __shfl(qy, src);
    const float vz = __shfl(qz, src);
    out[baseo + (size_t)(2 + 0 * 8 + m) * chs] = vw;
    out[baseo + (size_t)(2 + 1 * 8 + m) * chs] = vx;
    out[baseo + (size_t)(2 + 2 * 8 + m) * chs] = vy;
    out[baseo + (size_t)(2 + 3 * 8 + m) * chs] = vz;
  }
}

extern "C" void kernel_launch(void* const* d_in, const int* in_sizes, int n_in,
                              void* d_out, int out_size, void* d_ws, size_t ws_size,
                              hipStream_t stream) {
  const float* xyz     = (const float*)d_in[0];
  const float* new_xyz = (const float*)d_in[1];
  // d_in[2] (fps_idx) is dead: reference drops the fps column before use.
  float* out = (float*)d_out;
  // d_ws unused: single fused kernel, everything stays in registers/LDS.

  // 2 queries per wave, 4 waves per block -> 1024 blocks (4/CU, 16 waves/CU).
  hipLaunchKernelGGL(qgq_fused, dim3(NQ / 8), dim3(256), 0, stream,
                     xyz, new_xyz, out);
}